// Round 1
// baseline (527.862 us; speedup 1.0000x reference)
//
#include <hip/hip_runtime.h>
#include <math.h>

// Problem constants
#define B_     16
#define T_     60
#define N_     196
#define C_     512
#define SEGS_  10
#define TOPK_  6
#define TOPM_  12
#define HEADS_ 4
#define HD_    128
#define CLIP_  6
#define FRAMES_ 36

// workspace layout (float indices)
#define WS_Q   0      // 512 floats: q for batch 0
#define WS_SC  512    // 4*196 floats: scores[h][n] for b=0, f=0
#define WS_PID 1296   // 1 int: pid

#define SCALE_ 0.08838834764831845f  // 1/sqrt(128)

// ---------------------------------------------------------------------------
// Phase 1: q = qst_feat[0] @ Wq^T + bq   (512 dot-512)
// ---------------------------------------------------------------------------
__global__ void qproj_kernel(const float* __restrict__ qst,
                             const float* __restrict__ ipw,
                             const float* __restrict__ ipb,
                             float* __restrict__ ws) {
    __shared__ float x[C_];
    int tid = threadIdx.x;  // 256 threads
    x[tid]       = qst[tid];
    x[tid + 256] = qst[tid + 256];
    __syncthreads();
    const float4* x4 = (const float4*)x;
    for (int r = tid; r < C_; r += 256) {
        const float4* w4 = (const float4*)(ipw + (size_t)r * C_);
        float acc = 0.f;
        #pragma unroll 8
        for (int c = 0; c < C_ / 4; ++c) {
            float4 wv = w4[c], xv = x4[c];
            acc += wv.x * xv.x + wv.y * xv.y + wv.z * xv.z + wv.w * xv.w;
        }
        ws[WS_Q + r] = acc + ipb[r];
    }
}

// ---------------------------------------------------------------------------
// Phase 2: k[n] = patch_feat[0, fid0, n, :] @ Wk^T + bk ; scores[h][n]=q_h.k_h
// 49 blocks x 4 patches each, 256 threads
// ---------------------------------------------------------------------------
#define NPER 4
__global__ void score_kernel(const float* __restrict__ patch,
                             const int* __restrict__ tk,
                             const float* __restrict__ ipw,
                             const float* __restrict__ ipb,
                             float* __restrict__ ws) {
    __shared__ float xs[NPER][C_];
    __shared__ float qs[C_];
    __shared__ float kb[NPER][C_];
    int tid = threadIdx.x;
    int n0 = blockIdx.x * NPER;
    int fid0 = tk[0] * CLIP_;  // b=0, k=0, c=0
    const size_t base = (size_t)fid0 * N_ * C_;  // b = 0

    qs[tid]       = ws[WS_Q + tid];
    qs[tid + 256] = ws[WS_Q + tid + 256];
    for (int i = tid; i < NPER * C_; i += 256) {
        int n = i >> 9, c = i & (C_ - 1);
        xs[n][c] = patch[base + (size_t)(n0 + n) * C_ + c];
    }
    __syncthreads();

    // each thread computes k rows hd = tid and tid+256 for 4 patches
    float a0 = 0.f, a1 = 0.f, a2 = 0.f, a3 = 0.f;
    float b0 = 0.f, b1 = 0.f, b2 = 0.f, b3 = 0.f;
    {
        const float4* w0 = (const float4*)(ipw + (size_t)(C_ + tid) * C_);
        const float4* w1 = (const float4*)(ipw + (size_t)(C_ + tid + 256) * C_);
        const float4* x0 = (const float4*)xs[0];
        const float4* x1 = (const float4*)xs[1];
        const float4* x2 = (const float4*)xs[2];
        const float4* x3 = (const float4*)xs[3];
        for (int c = 0; c < C_ / 4; ++c) {
            float4 wa = w0[c], wb = w1[c];
            float4 v0 = x0[c], v1 = x1[c], v2 = x2[c], v3 = x3[c];
            a0 += wa.x * v0.x + wa.y * v0.y + wa.z * v0.z + wa.w * v0.w;
            a1 += wa.x * v1.x + wa.y * v1.y + wa.z * v1.z + wa.w * v1.w;
            a2 += wa.x * v2.x + wa.y * v2.y + wa.z * v2.z + wa.w * v2.w;
            a3 += wa.x * v3.x + wa.y * v3.y + wa.z * v3.z + wa.w * v3.w;
            b0 += wb.x * v0.x + wb.y * v0.y + wb.z * v0.z + wb.w * v0.w;
            b1 += wb.x * v1.x + wb.y * v1.y + wb.z * v1.z + wb.w * v1.w;
            b2 += wb.x * v2.x + wb.y * v2.y + wb.z * v2.z + wb.w * v2.w;
            b3 += wb.x * v3.x + wb.y * v3.y + wb.z * v3.z + wb.w * v3.w;
        }
    }
    float bk0 = ipb[C_ + tid];
    float bk1 = ipb[C_ + tid + 256];
    kb[0][tid] = a0 + bk0; kb[1][tid] = a1 + bk0;
    kb[2][tid] = a2 + bk0; kb[3][tid] = a3 + bk0;
    kb[0][tid + 256] = b0 + bk1; kb[1][tid + 256] = b1 + bk1;
    kb[2][tid + 256] = b2 + bk1; kb[3][tid + 256] = b3 + bk1;
    __syncthreads();

    // scores: wave h (4 waves) reduces 128 products per patch
    int h = tid >> 6, j = tid & 63;
    for (int nn = 0; nn < NPER; ++nn) {
        float p = qs[h * HD_ + j]      * kb[nn][h * HD_ + j]
                + qs[h * HD_ + 64 + j] * kb[nn][h * HD_ + 64 + j];
        for (int off = 32; off; off >>= 1) p += __shfl_down(p, off);
        if (j == 0) ws[WS_SC + h * N_ + n0 + nn] = p * SCALE_;
    }
}

// ---------------------------------------------------------------------------
// Phase 3: softmax per head over n, mean over heads, top-12 -> pid
// ---------------------------------------------------------------------------
__global__ void pid_kernel(float* __restrict__ ws) {
    __shared__ float wgt[HEADS_][N_];
    __shared__ float pw[N_];
    int tid = threadIdx.x;  // 256
    int h = tid >> 6, j = tid & 63;

    // wave h handles head h: lanes own n = j + 64*s
    float sc[4]; float ex[4];
    int m = 0;
    float mx = -1e30f;
    for (int n = j; n < N_; n += 64) {
        sc[m] = ws[WS_SC + h * N_ + n];
        mx = fmaxf(mx, sc[m]);
        ++m;
    }
    for (int off = 1; off < 64; off <<= 1) mx = fmaxf(mx, __shfl_xor(mx, off));
    float sum = 0.f;
    for (int s = 0; s < m; ++s) { ex[s] = expf(sc[s] - mx); sum += ex[s]; }
    for (int off = 1; off < 64; off <<= 1) sum += __shfl_xor(sum, off);
    float inv = 1.f / sum;
    m = 0;
    for (int n = j; n < N_; n += 64) { wgt[h][n] = ex[m] * inv; ++m; }
    __syncthreads();

    for (int n = tid; n < N_; n += 256)
        pw[n] = 0.25f * (wgt[0][n] + wgt[1][n] + wgt[2][n] + wgt[3][n]);
    __syncthreads();

    // wave 0: 12 rounds of parallel argmax; ties prefer larger index
    // (stable ascending argsort + take-last => larger index wins at boundary)
    if (tid < 64) {
        float v[4];
        for (int s = 0; s < 4; ++s) {
            int n = j + 64 * s;
            v[s] = (n < N_) ? pw[n] : -1e30f;
        }
        int pid = -1;
        for (int r = 0; r < TOPM_; ++r) {
            float bv = -1e30f; int bi = -1;
            for (int s = 0; s < 4; ++s) {
                int n = j + 64 * s;
                if (v[s] > bv || (v[s] == bv && n > bi)) { bv = v[s]; bi = n; }
            }
            for (int off = 1; off < 64; off <<= 1) {
                float ov = __shfl_xor(bv, off);
                int   oi = __shfl_xor(bi, off);
                if (ov > bv || (ov == bv && oi > bi)) { bv = ov; bi = oi; }
            }
            if ((bi & 63) == j) v[bi >> 6] = -1e30f;
            if (bi > pid) pid = bi;
        }
        if (j == 0) ((int*)ws)[WS_PID] = pid;
    }
}

// ---------------------------------------------------------------------------
// Phase 4: gather outputs.
// out0 = audio_feat[b, fid, :]                         (B,F,C)
// out1 = patch_feat[b, fid, pid, :] bcast x12          (B,F,12,C)
// out2 = same reshaped                                 (B,F*12,C)
// ---------------------------------------------------------------------------
__global__ void out_kernel(const float* __restrict__ audio,
                           const float* __restrict__ patch,
                           const int* __restrict__ tk,
                           const float* __restrict__ ws,
                           float* __restrict__ out) {
    int bf = blockIdx.x;               // 0 .. B*FRAMES-1
    int b = bf / FRAMES_, f = bf % FRAMES_;
    int k = f / CLIP_, c = f % CLIP_;
    int fid = tk[b * TOPK_ + k] * CLIP_ + c;
    int t = threadIdx.x;               // 0..127, float4 lanes over C
    int pid = ((const int*)ws)[WS_PID];

    const float4* a4 = (const float4*)(audio + ((size_t)b * T_ + fid) * C_);
    const float4* p4 = (const float4*)(patch + (((size_t)b * T_ + fid) * N_ + pid) * C_);
    float4 av = a4[t];
    float4 sv = p4[t];

    float4* o0 = (float4*)out;
    float4* o1 = (float4*)(out + (size_t)B_ * FRAMES_ * C_);
    float4* o2 = (float4*)(out + (size_t)B_ * FRAMES_ * C_ + (size_t)B_ * FRAMES_ * TOPM_ * C_);

    o0[(size_t)bf * (C_ / 4) + t] = av;
    size_t rb = (size_t)bf * TOPM_ * (C_ / 4);
    #pragma unroll
    for (int mm = 0; mm < TOPM_; ++mm) {
        o1[rb + mm * (C_ / 4) + t] = sv;
        o2[rb + mm * (C_ / 4) + t] = sv;
    }
}

extern "C" void kernel_launch(void* const* d_in, const int* in_sizes, int n_in,
                              void* d_out, int out_size, void* d_ws, size_t ws_size,
                              hipStream_t stream) {
    const float* audio = (const float*)d_in[0];   // (B,T,C)
    const float* patch = (const float*)d_in[1];   // (B,T,N,C)
    const float* qst   = (const float*)d_in[2];   // (B,C)
    const int*   tk    = (const int*)d_in[3];     // (B,1,TOP_K)
    const float* ipw   = (const float*)d_in[4];   // (3C,C)
    const float* ipb   = (const float*)d_in[5];   // (3C,)
    // d_in[6..13] (out_w/out_b/lin1/lin2/ln) are dead w.r.t. the returned outputs
    float* out = (float*)d_out;
    float* ws  = (float*)d_ws;

    qproj_kernel<<<1, 256, 0, stream>>>(qst, ipw, ipb, ws);
    score_kernel<<<N_ / NPER, 256, 0, stream>>>(patch, tk, ipw, ipb, ws);
    pid_kernel<<<1, 256, 0, stream>>>(ws);
    out_kernel<<<B_ * FRAMES_, 128, 0, stream>>>(audio, patch, tk, ws, out);
}